// Round 8
// baseline (1006.547 us; speedup 1.0000x reference)
//
#include <hip/hip_runtime.h>
#include <cmath>

// WaterNet: NH=128, NG=32, NR=15, NT=730, NS=800
#define NHID 128
#define NSITE 800
#define NTIME 730
#define NRTAP 15
#define SPB 4            // sites per block
#define TB 16            // timesteps per batch
#define NBAT 46          // ceil(730/16)
constexpr int NSH = NSITE * NHID;  // 102400

typedef _Float16 f16x8 __attribute__((ext_vector_type(8)));
typedef float f32x4 __attribute__((ext_vector_type(4)));

__device__ __forceinline__ float tanh_fast(float x) {
    float e = __expf(2.0f * x);
    return 1.0f - 2.0f / (e + 1.0f);
}
__device__ __forceinline__ float sigmoid_fast(float x) {
    return 1.0f / (1.0f + __expf(-x));
}
// Swizzled index into A-fragment LDS tile: jg = k-octet (0..31), r = row (0..63).
// Conflict-free for L1 write and MFMA read (verified r7: SQ_LDS_BANK_CONFLICT = 0).
__device__ __forceinline__ int ah_swz(int jg, int r) {
    return jg * 64 + ((r & ~7) | ((r ^ jg) & 7));
}

// ---------------------------------------------------------------------------
// P0: fcT2_w (fp32 [256][384]) -> fp16 MFMA layout w2s[K0][kg][col][e]
// ---------------------------------------------------------------------------
__global__ void k_prep_w2h(const float* __restrict__ w2, _Float16* __restrict__ w2s)
{
    int idx = blockIdx.x * 256 + threadIdx.x;
    if (idx >= 98304) return;
    int k = idx / 384, col = idx - k * 384;
    int K0 = k >> 5, kg = (k >> 3) & 3, e = k & 7;
    w2s[(size_t)K0 * 12288 + kg * 3072 + col * 8 + e] = (_Float16)w2[(size_t)k * 384 + col];
}

// ---------------------------------------------------------------------------
// A1: per-site layer-1 for all three heads.
// ---------------------------------------------------------------------------
__global__ void k_site_l1(const float* __restrict__ xc,
                          const float* __restrict__ w1W, const float* __restrict__ b1W,
                          const float* __restrict__ w1R, const float* __restrict__ b1R,
                          const float* __restrict__ w1T, const float* __restrict__ b1T,
                          float* __restrict__ h1w, float* __restrict__ h1r,
                          float* __restrict__ basec)
{
    __shared__ float xr[32];
    int s = blockIdx.x, j = threadIdx.x;
    if (j < 32) xr[j] = xc[s * 32 + j];
    __syncthreads();
    float aW = b1W[j], aR = b1R[j], aT = b1T[j];
#pragma unroll 8
    for (int k = 0; k < 32; ++k) {
        float xv = xr[k];
        aW = fmaf(xv, w1W[k * 256 + j], aW);
        aR = fmaf(xv, w1R[k * 256 + j], aR);
        aT = fmaf(xv, w1T[(6 + k) * 256 + j], aT);
    }
    h1w[s * 256 + j]   = tanh_fast(aW);
    h1r[s * 256 + j]   = tanh_fast(aR);
    basec[s * 256 + j] = aT;
}

// ---------------------------------------------------------------------------
// A2: static parameter head layer-2 + activations.
// ---------------------------------------------------------------------------
__global__ void k_whead(const float* __restrict__ h1w,
                        const float* __restrict__ w2, const float* __restrict__ b2,
                        float* __restrict__ params)
{
    __shared__ float h[8 * 256];
    int sBase = blockIdx.x * 8, g = blockIdx.y, tid = threadIdx.x;
    for (int p = tid; p < 2048; p += 128) h[p] = h1w[sBase * 256 + p];
    __syncthreads();
    float bias = b2[g * 128 + tid];
    float acc[8];
#pragma unroll
    for (int i = 0; i < 8; ++i) acc[i] = bias;
    for (int k = 0; k < 256; ++k) {
        float wv = w2[k * 896 + g * 128 + tid];
#pragma unroll
        for (int i = 0; i < 8; ++i) acc[i] = fmaf(h[i * 256 + k], wv, acc[i]);
    }
#pragma unroll
    for (int i = 0; i < 8; ++i) {
        float v = acc[i], o;
        if (g == 0 || g == 1 || g == 3)  o = sigmoid_fast(v);
        else if (g == 2)                 o = sigmoid_fast(v) * 0.1f;
        else if (g == 4)                 o = __expf(v) * 2.0f;
        else if (g == 5)                 o = fmaxf(v, 0.0f);
        else                             o = v;
        params[g * NSH + (sBase + i) * 128 + tid] = o;
    }
}

// ---------------------------------------------------------------------------
// A3: softmax of ga over 128 buckets, in place.
// ---------------------------------------------------------------------------
__global__ void k_softmax_ga(float* __restrict__ ga)
{
    int s = blockIdx.x, h = threadIdx.x;
    float v = ga[s * 128 + h];
    float m = v;
#pragma unroll
    for (int off = 32; off; off >>= 1) m = fmaxf(m, __shfl_xor(m, off));
    __shared__ float ra[2], rb[2];
    if ((h & 63) == 0) ra[h >> 6] = m;
    __syncthreads();
    m = fmaxf(ra[0], ra[1]);
    float e = __expf(v - m);
    float t = e;
#pragma unroll
    for (int off = 32; off; off >>= 1) t += __shfl_xor(t, off);
    if ((h & 63) == 0) rb[h >> 6] = t;
    __syncthreads();
    ga[s * 128 + h] = e / (rb[0] + rb[1]);
}

// ---------------------------------------------------------------------------
// A4: routing head layer-2, relu, [NRTAP][NSITE*NHID]
// ---------------------------------------------------------------------------
__global__ void k_rhead(const float* __restrict__ h1r,
                        const float* __restrict__ w2, const float* __restrict__ b2,
                        float* __restrict__ rbuf)
{
    __shared__ float h[8 * 256];
    int sBase = blockIdx.x * 8, g = blockIdx.y, tid = threadIdx.x;
    for (int p = tid; p < 2048; p += 128) h[p] = h1r[sBase * 256 + p];
    __syncthreads();
    int c = g * 128 + tid;
    float bias = b2[c];
    float acc[8];
#pragma unroll
    for (int i = 0; i < 8; ++i) acc[i] = bias;
    for (int k = 0; k < 256; ++k) {
        float wv = w2[k * 1920 + c];
#pragma unroll
        for (int i = 0; i < 8; ++i) acc[i] = fmaf(h[i * 256 + k], wv, acc[i]);
    }
    int hh = c / 15, ii = c - hh * 15;
#pragma unroll
    for (int i = 0; i < 8; ++i)
        rbuf[ii * NSH + (sBase + i) * 128 + hh] = fmaxf(acc[i], 0.0f);
}

// ---------------------------------------------------------------------------
// FUSED v3: 200 blocks x 512 threads, all co-resident (1 block/CU).
// Block owns 4 sites for all 730 steps; 46 batches of TB=16:
//   L1 (rows = 4 sites x 16 t) -> 96 MFMA (B held ENTIRELY in VGPRs,
//   loaded once -- no w2 re-fetch, r6's 2.1 GB HBM leak) -> epilogue to LDS
//   -> 16 scan steps (all 512 threads; 4x128 cells).
// Per-batch global traffic: 24 B/thread of x (prefetched one batch ahead).
// ---------------------------------------------------------------------------
__global__ __launch_bounds__(512, 1) void k_fused3(
    const float* __restrict__ x, const float* __restrict__ w1T,
    const float* __restrict__ basec, const f16x8* __restrict__ w2B,
    const float* __restrict__ b2, const float* __restrict__ params,
    const float* __restrict__ rbuf, float* __restrict__ out)
{
    __shared__ f16x8 Ah[2048];                // 32 KB swizzled A fragments
    __shared__ _Float16 sio[3][64][136];      // 52.2 KB epilogue buffer
    __shared__ float xt[64][6];
    __shared__ float pls[64], evs[64], psv[64];
    __shared__ float part[8][TB];

    int tid = threadIdx.x;
    int s0 = blockIdx.x * SPB;
    int lane = tid & 63, wid = tid >> 6;
    int l15 = lane & 15, l4 = lane >> 4;
    int n0w = wid * 48;                       // 8 waves x 48 cols = 384
    int jg = tid & 31, rg = tid >> 5;         // L1: k-octet, row-quad
    int j0 = jg * 8;
    int r0 = rg * 4;
    int slA = rg >> 2;                        // the ONE site this thread's L1 rows use

    // ---- persistent B fragments: the whole w2 in registers (96 VGPR) ----
    f16x8 bfk[8][3];
#pragma unroll
    for (int ks = 0; ks < 8; ++ks)
#pragma unroll
        for (int nf = 0; nf < 3; ++nf)
            bfk[ks][nf] = w2B[(size_t)ks * 1536 + l4 * 384 + n0w + nf * 16 + l15];

    float bbias[3];
#pragma unroll
    for (int nf = 0; nf < 3; ++nf) bbias[nf] = b2[n0w + nf * 16 + l15];

    // ---- persistent basec slice (batch-invariant: 8 floats) ----
    float bcv[8];
    {
        const float* bp = &basec[(size_t)(s0 + slA) * 256 + j0];
        float4 b0 = *(const float4*)bp;
        float4 b1 = *(const float4*)(bp + 4);
        bcv[0] = b0.x; bcv[1] = b0.y; bcv[2] = b0.z; bcv[3] = b0.w;
        bcv[4] = b1.x; bcv[5] = b1.y; bcv[6] = b1.z; bcv[7] = b1.w;
    }

    // ---- persistent scan state: thread owns cell (site sl, bucket hc) ----
    int sl = tid >> 7, hc = tid & 127;
    int cell = (s0 + sl) * 128 + hc;
    float kp  = params[0 * NSH + cell];
    float ksP = params[1 * NSH + cell];
    float kgP = params[2 * NSH + cell];
    float gp  = params[3 * NSH + cell];
    float gL  = params[4 * NSH + cell];
    float qb  = params[5 * NSH + cell];
    float ga  = params[6 * NSH + cell];
    float kq  = ksP * (1.0f - gp);
    float wr[NRTAP];
#pragma unroll
    for (int i = 0; i < NRTAP; ++i) wr[i] = ga * rbuf[i * NSH + cell];
    float Sf = 0.0f, Ss = 0.0f, Sg = 0.0f, f[NRTAP];
#pragma unroll
    for (int i = 0; i < NRTAP; ++i) f[i] = 0.0f;

    // ---- x prefetch registers (threads 0..63; row = sl*16 + tl) ----
    float xr6[6];
    if (tid < 64) {
        int t = tid & 15;                    // batch 0
        int tt = (t < NTIME) ? t : NTIME - 1;
        const float* xp = &x[((size_t)tt * 800 + s0 + (tid >> 4)) * 6];
#pragma unroll
        for (int c = 0; c < 6; ++c) xr6[c] = xp[c];
    }

    for (int b = 0; b < NBAT; ++b) {
        int t0 = b * TB;
        int nst = NTIME - t0; if (nst > TB) nst = TB;

        // w1 slice loads (global, L2-hot; in flight across stage + barrier)
        float4 wA[6], wB[6];
#pragma unroll
        for (int c = 0; c < 6; ++c) {
            wA[c] = *(const float4*)&w1T[c * 256 + j0];
            wB[c] = *(const float4*)&w1T[c * 256 + j0 + 4];
        }

        // ---- stage: xr6 -> xt + snow-fraction scalars ----
        if (tid < 64) {
            int tl = tid & 15;
            bool ok = (t0 + tl) < NTIME;
            float P = xr6[0], E = xr6[1], T1 = xr6[2], T2 = xr6[3];
#pragma unroll
            for (int c = 0; c < 6; ++c) xt[tid][c] = xr6[c];
            float den = T2 - T1;
            float cf = (T1 + T2) / ((den == 0.0f) ? 1.0f : den);
            cf = fminf(fmaxf(cf, -0.999999f), 0.999999f);
            float vf = acosf(cf) * (1.0f / 3.1415f);
            vf = (T1 >= 0.0f) ? 0.0f : vf;
            vf = (T2 <= 0.0f) ? 1.0f : vf;
            pls[tid] = ok ? P * (1.0f - vf) : 0.0f;
            evs[tid] = ok ? E : 0.0f;
            psv[tid] = ok ? P * vf : 0.0f;
        }
        __syncthreads();   // B1: xt ready

        // prefetch x for next batch (latency hidden under L1+GEMM+scan)
        if (b + 1 < NBAT && tid < 64) {
            int t = (b + 1) * TB + (tid & 15);
            int tt = (t < NTIME) ? t : NTIME - 1;
            const float* xp = &x[((size_t)tt * 800 + s0 + (tid >> 4)) * 6];
#pragma unroll
            for (int c = 0; c < 6; ++c) xr6[c] = xp[c];
        }

        // ---- L1: 4 rows x 8 k-elems -> swizzled Ah ----
#pragma unroll
        for (int rr = 0; rr < 4; ++rr) {
            int r = r0 + rr;
            float a[8];
            a[0] = bcv[0]; a[1] = bcv[1]; a[2] = bcv[2]; a[3] = bcv[3];
            a[4] = bcv[4]; a[5] = bcv[5]; a[6] = bcv[6]; a[7] = bcv[7];
#pragma unroll
            for (int c = 0; c < 6; ++c) {
                float xv = xt[r][c];
                a[0] = fmaf(xv, wA[c].x, a[0]);
                a[1] = fmaf(xv, wA[c].y, a[1]);
                a[2] = fmaf(xv, wA[c].z, a[2]);
                a[3] = fmaf(xv, wA[c].w, a[3]);
                a[4] = fmaf(xv, wB[c].x, a[4]);
                a[5] = fmaf(xv, wB[c].y, a[5]);
                a[6] = fmaf(xv, wB[c].z, a[6]);
                a[7] = fmaf(xv, wB[c].w, a[7]);
            }
            f16x8 hv;
#pragma unroll
            for (int e = 0; e < 8; ++e) hv[e] = (_Float16)tanh_fast(a[e]);
            Ah[ah_swz(jg, r)] = hv;
        }
        __syncthreads();   // B2: Ah ready

        // ---- GEMM: 96 MFMA, B from persistent registers, no barriers ----
        f32x4 acc[4][3];
#pragma unroll
        for (int nf = 0; nf < 3; ++nf) {
            float bb = bbias[nf];
#pragma unroll
            for (int mf = 0; mf < 4; ++mf) acc[mf][nf] = (f32x4){bb, bb, bb, bb};
        }
#pragma unroll
        for (int ks = 0; ks < 8; ++ks) {
            f16x8 af[4];
#pragma unroll
            for (int mf = 0; mf < 4; ++mf)
                af[mf] = Ah[ah_swz(ks * 4 + l4, mf * 16 + l15)];
#pragma unroll
            for (int mf = 0; mf < 4; ++mf)
#pragma unroll
                for (int nf = 0; nf < 3; ++nf)
                    acc[mf][nf] = __builtin_amdgcn_mfma_f32_16x16x32_f16(
                        af[mf], bfk[ks][nf], acc[mf][nf], 0, 0, 0);
        }

        // ---- epilogue: activations + forcing folding -> sio ----
#pragma unroll
        for (int mf = 0; mf < 4; ++mf) {
#pragma unroll
            for (int nf = 0; nf < 3; ++nf) {
                int colg = n0w + nf * 16 + l15;
                int ch = colg >> 7, cl = colg & 127;
#pragma unroll
                for (int rr = 0; rr < 4; ++rr) {
                    int r = mf * 16 + l4 * 4 + rr;
                    float v = acc[mf][nf][rr];
                    float o;
                    if (ch == 0)
                        o = pls[r] * fminf(fmaxf(v * (1.0f / 3.0f) + 0.5f, 0.0f), 1.0f);
                    else if (ch == 1)
                        o = evs[r] * fmaxf(v, 0.0f) * 2.0f;
                    else
                        o = fminf(__expf(v), 60000.0f);
                    sio[ch][r][cl] = (_Float16)o;
                }
            }
        }
        __syncthreads();   // B3: sio ready

        // ---- scan: 16 steps, all 512 threads; reductions batched after ----
        float cs[TB];
#pragma unroll
        for (int t = 0; t < TB; ++t) {
            cs[t] = 0.0f;
            if (t < nst) {
                int r = sl * 16 + t;
                float pl = (float)sio[0][r][hc];
                float ev = (float)sio[1][r][hc];
                float vm = (float)sio[2][r][hc];
                float ps = psv[r];

                float x1 = Sf + ps;
                float qf = fminf(x1, vm);
                Sf = fmaxf(x1 - vm, 0.0f);
                float H  = fmaxf(Ss + pl + qf - ev, 0.0f);
                float qp = fmaxf(kp * (H - gL), 0.0f);
                float mh = fminf(H, gL);
                float qs = ksP * mh;
                Ss = H - qp - qs;
                float qg = fmaf(kgP, fmaf(qs, gp, Sg), qb);
                Sg = Sg - qg;
                float qt = qp + kq * mh + qg;

#pragma unroll
                for (int j = 0; j < NRTAP; ++j) f[j] = fmaf(wr[j], qt, f[j]);
                cs[t] = f[0];
#pragma unroll
                for (int j = 0; j < NRTAP - 1; ++j) f[j] = f[j + 1];
                f[NRTAP - 1] = 0.0f;
            }
        }
        // 16 independent wave reductions (shfl latency overlapped)
#pragma unroll
        for (int t = 0; t < TB; ++t) {
            float c = cs[t];
#pragma unroll
            for (int off = 32; off; off >>= 1) c += __shfl_xor(c, off);
            cs[t] = c;
        }
        if (lane == 0) {
#pragma unroll
            for (int t = 0; t < TB; ++t) part[wid][t] = cs[t];
        }
        __syncthreads();   // B4: partials ready, sio/xt free

        if (tid < 64) {
            int osl = tid >> 4, t = tid & 15;
            if (t < nst)
                out[(size_t)(t0 + t) * 800 + s0 + osl] =
                    part[osl * 2][t] + part[osl * 2 + 1][t];
        }
    }
}

// ---------------------------------------------------------------------------
extern "C" void kernel_launch(void* const* d_in, const int* in_sizes, int n_in,
                              void* d_out, int out_size, void* d_ws, size_t ws_size,
                              hipStream_t stream)
{
    const float* x      = (const float*)d_in[0];
    const float* xc     = (const float*)d_in[1];
    const float* fcW1_w = (const float*)d_in[2];
    const float* fcW1_b = (const float*)d_in[3];
    const float* fcW2_w = (const float*)d_in[4];
    const float* fcW2_b = (const float*)d_in[5];
    const float* fcT1_w = (const float*)d_in[6];
    const float* fcT1_b = (const float*)d_in[7];
    const float* fcT2_w = (const float*)d_in[8];
    const float* fcT2_b = (const float*)d_in[9];
    const float* fcR1_w = (const float*)d_in[10];
    const float* fcR1_b = (const float*)d_in[11];
    const float* fcR2_w = (const float*)d_in[12];
    const float* fcR2_b = (const float*)d_in[13];
    float* out = (float*)d_out;

    char* wsb = (char*)d_ws;
    size_t off = 0;
    float* params = (float*)(wsb + off); off += (size_t)7 * NSH * 4;
    float* rbuf   = (float*)(wsb + off); off += (size_t)NRTAP * NSH * 4;
    float* basec  = (float*)(wsb + off); off += 800 * 256 * 4;
    float* h1w    = (float*)(wsb + off); off += 800 * 256 * 4;
    float* h1r    = (float*)(wsb + off); off += 800 * 256 * 4;
    _Float16* w2s = (_Float16*)(wsb + off); off += 98304 * 2;

    k_prep_w2h<<<384, 256, 0, stream>>>(fcT2_w, w2s);
    k_site_l1<<<800, 256, 0, stream>>>(xc, fcW1_w, fcW1_b, fcR1_w, fcR1_b,
                                       fcT1_w, fcT1_b, h1w, h1r, basec);
    k_whead<<<dim3(100, 7), 128, 0, stream>>>(h1w, fcW2_w, fcW2_b, params);
    k_softmax_ga<<<800, 128, 0, stream>>>(params + (size_t)6 * NSH);
    k_rhead<<<dim3(100, 15), 128, 0, stream>>>(h1r, fcR2_w, fcR2_b, rbuf);

    k_fused3<<<NSITE / SPB, 512, 0, stream>>>(
        x, fcT1_w, basec, (const f16x8*)w2s, fcT2_b, params, rbuf, out);
}

// Round 9
// 1004.704 us; speedup vs baseline: 1.0018x; 1.0018x over previous
//
#include <hip/hip_runtime.h>
#include <cmath>

// WaterNet: NH=128, NG=32, NR=15, NT=730, NS=800
#define NHID 128
#define NSITE 800
#define NTIME 730
#define NRTAP 15
#define SPB 4            // sites per block
#define TB 16            // timesteps per batch
#define NBAT 46          // ceil(730/16)
constexpr int NSH = NSITE * NHID;  // 102400

typedef _Float16 f16x8 __attribute__((ext_vector_type(8)));
typedef float f32x4 __attribute__((ext_vector_type(4)));

__device__ __forceinline__ float tanh_fast(float x) {
    float e = __expf(2.0f * x);
    return 1.0f - 2.0f / (e + 1.0f);
}
__device__ __forceinline__ float sigmoid_fast(float x) {
    return 1.0f / (1.0f + __expf(-x));
}
// Swizzled index into A-fragment LDS tile: jg = k-octet (0..31), r = row (0..63).
// Conflict-free for L1 write and MFMA read (verified r7: SQ_LDS_BANK_CONFLICT = 0).
__device__ __forceinline__ int ah_swz(int jg, int r) {
    return jg * 64 + ((r & ~7) | ((r ^ jg) & 7));
}

// ---------------------------------------------------------------------------
// P0: fcT2_w (fp32 [256][384]) -> fp16 MFMA layout w2s[K0][kg][col][e]
// ---------------------------------------------------------------------------
__global__ void k_prep_w2h(const float* __restrict__ w2, _Float16* __restrict__ w2s)
{
    int idx = blockIdx.x * 256 + threadIdx.x;
    if (idx >= 98304) return;
    int k = idx / 384, col = idx - k * 384;
    int K0 = k >> 5, kg = (k >> 3) & 3, e = k & 7;
    w2s[(size_t)K0 * 12288 + kg * 3072 + col * 8 + e] = (_Float16)w2[(size_t)k * 384 + col];
}

// ---------------------------------------------------------------------------
// A1: per-site layer-1 for all three heads.
// ---------------------------------------------------------------------------
__global__ void k_site_l1(const float* __restrict__ xc,
                          const float* __restrict__ w1W, const float* __restrict__ b1W,
                          const float* __restrict__ w1R, const float* __restrict__ b1R,
                          const float* __restrict__ w1T, const float* __restrict__ b1T,
                          float* __restrict__ h1w, float* __restrict__ h1r,
                          float* __restrict__ basec)
{
    __shared__ float xr[32];
    int s = blockIdx.x, j = threadIdx.x;
    if (j < 32) xr[j] = xc[s * 32 + j];
    __syncthreads();
    float aW = b1W[j], aR = b1R[j], aT = b1T[j];
#pragma unroll 8
    for (int k = 0; k < 32; ++k) {
        float xv = xr[k];
        aW = fmaf(xv, w1W[k * 256 + j], aW);
        aR = fmaf(xv, w1R[k * 256 + j], aR);
        aT = fmaf(xv, w1T[(6 + k) * 256 + j], aT);
    }
    h1w[s * 256 + j]   = tanh_fast(aW);
    h1r[s * 256 + j]   = tanh_fast(aR);
    basec[s * 256 + j] = aT;
}

// ---------------------------------------------------------------------------
// A2: static parameter head layer-2 + activations.
// ---------------------------------------------------------------------------
__global__ void k_whead(const float* __restrict__ h1w,
                        const float* __restrict__ w2, const float* __restrict__ b2,
                        float* __restrict__ params)
{
    __shared__ float h[8 * 256];
    int sBase = blockIdx.x * 8, g = blockIdx.y, tid = threadIdx.x;
    for (int p = tid; p < 2048; p += 128) h[p] = h1w[sBase * 256 + p];
    __syncthreads();
    float bias = b2[g * 128 + tid];
    float acc[8];
#pragma unroll
    for (int i = 0; i < 8; ++i) acc[i] = bias;
    for (int k = 0; k < 256; ++k) {
        float wv = w2[k * 896 + g * 128 + tid];
#pragma unroll
        for (int i = 0; i < 8; ++i) acc[i] = fmaf(h[i * 256 + k], wv, acc[i]);
    }
#pragma unroll
    for (int i = 0; i < 8; ++i) {
        float v = acc[i], o;
        if (g == 0 || g == 1 || g == 3)  o = sigmoid_fast(v);
        else if (g == 2)                 o = sigmoid_fast(v) * 0.1f;
        else if (g == 4)                 o = __expf(v) * 2.0f;
        else if (g == 5)                 o = fmaxf(v, 0.0f);
        else                             o = v;
        params[g * NSH + (sBase + i) * 128 + tid] = o;
    }
}

// ---------------------------------------------------------------------------
// A3: softmax of ga over 128 buckets, in place.
// ---------------------------------------------------------------------------
__global__ void k_softmax_ga(float* __restrict__ ga)
{
    int s = blockIdx.x, h = threadIdx.x;
    float v = ga[s * 128 + h];
    float m = v;
#pragma unroll
    for (int off = 32; off; off >>= 1) m = fmaxf(m, __shfl_xor(m, off));
    __shared__ float ra[2], rb[2];
    if ((h & 63) == 0) ra[h >> 6] = m;
    __syncthreads();
    m = fmaxf(ra[0], ra[1]);
    float e = __expf(v - m);
    float t = e;
#pragma unroll
    for (int off = 32; off; off >>= 1) t += __shfl_xor(t, off);
    if ((h & 63) == 0) rb[h >> 6] = t;
    __syncthreads();
    ga[s * 128 + h] = e / (rb[0] + rb[1]);
}

// ---------------------------------------------------------------------------
// A4: routing head layer-2, relu, [NRTAP][NSITE*NHID]
// ---------------------------------------------------------------------------
__global__ void k_rhead(const float* __restrict__ h1r,
                        const float* __restrict__ w2, const float* __restrict__ b2,
                        float* __restrict__ rbuf)
{
    __shared__ float h[8 * 256];
    int sBase = blockIdx.x * 8, g = blockIdx.y, tid = threadIdx.x;
    for (int p = tid; p < 2048; p += 128) h[p] = h1r[sBase * 256 + p];
    __syncthreads();
    int c = g * 128 + tid;
    float bias = b2[c];
    float acc[8];
#pragma unroll
    for (int i = 0; i < 8; ++i) acc[i] = bias;
    for (int k = 0; k < 256; ++k) {
        float wv = w2[k * 1920 + c];
#pragma unroll
        for (int i = 0; i < 8; ++i) acc[i] = fmaf(h[i * 256 + k], wv, acc[i]);
    }
    int hh = c / 15, ii = c - hh * 15;
#pragma unroll
    for (int i = 0; i < 8; ++i)
        rbuf[ii * NSH + (sBase + i) * 128 + hh] = fmaxf(acc[i], 0.0f);
}

// ---------------------------------------------------------------------------
// FUSED v3b: identical structure to r8, but with the register budget the
// design actually needs: __launch_bounds__(512, 2) -> 2 waves/SIMD -> 256
// VGPR cap. The persistent B fragments (96 VGPR) + acc (48) + scan state
// (~40) fit without spilling (r8 spilled at the default 128 cap: FETCH
// 598 MB of scratch re-reads, VALUBusy 3%).
// ---------------------------------------------------------------------------
__global__ __launch_bounds__(512, 2) void k_fused3(
    const float* __restrict__ x, const float* __restrict__ w1T,
    const float* __restrict__ basec, const f16x8* __restrict__ w2B,
    const float* __restrict__ b2, const float* __restrict__ params,
    const float* __restrict__ rbuf, float* __restrict__ out)
{
    __shared__ f16x8 Ah[2048];                // 32 KB swizzled A fragments
    __shared__ _Float16 sio[3][64][136];      // 52.2 KB epilogue buffer
    __shared__ float xt[64][6];
    __shared__ float pls[64], evs[64], psv[64];
    __shared__ float part[8][TB];

    int tid = threadIdx.x;
    int s0 = blockIdx.x * SPB;
    int lane = tid & 63, wid = tid >> 6;
    int l15 = lane & 15, l4 = lane >> 4;
    int n0w = wid * 48;                       // 8 waves x 48 cols = 384
    int jg = tid & 31, rg = tid >> 5;         // L1: k-octet, row-quad
    int j0 = jg * 8;
    int r0 = rg * 4;
    int slA = rg >> 2;                        // the ONE site this thread's L1 rows use

    // ---- persistent B fragments: the whole w2 in registers (96 VGPR) ----
    f16x8 bfk[8][3];
#pragma unroll
    for (int ks = 0; ks < 8; ++ks)
#pragma unroll
        for (int nf = 0; nf < 3; ++nf)
            bfk[ks][nf] = w2B[(size_t)ks * 1536 + l4 * 384 + n0w + nf * 16 + l15];

    float bbias[3];
#pragma unroll
    for (int nf = 0; nf < 3; ++nf) bbias[nf] = b2[n0w + nf * 16 + l15];

    // ---- persistent basec slice (batch-invariant: 8 floats) ----
    float bcv[8];
    {
        const float* bp = &basec[(size_t)(s0 + slA) * 256 + j0];
        float4 b0 = *(const float4*)bp;
        float4 b1 = *(const float4*)(bp + 4);
        bcv[0] = b0.x; bcv[1] = b0.y; bcv[2] = b0.z; bcv[3] = b0.w;
        bcv[4] = b1.x; bcv[5] = b1.y; bcv[6] = b1.z; bcv[7] = b1.w;
    }

    // ---- persistent scan state: thread owns cell (site sl, bucket hc) ----
    int sl = tid >> 7, hc = tid & 127;
    int cell = (s0 + sl) * 128 + hc;
    float kp  = params[0 * NSH + cell];
    float ksP = params[1 * NSH + cell];
    float kgP = params[2 * NSH + cell];
    float gp  = params[3 * NSH + cell];
    float gL  = params[4 * NSH + cell];
    float qb  = params[5 * NSH + cell];
    float ga  = params[6 * NSH + cell];
    float kq  = ksP * (1.0f - gp);
    float wr[NRTAP];
#pragma unroll
    for (int i = 0; i < NRTAP; ++i) wr[i] = ga * rbuf[i * NSH + cell];
    float Sf = 0.0f, Ss = 0.0f, Sg = 0.0f, f[NRTAP];
#pragma unroll
    for (int i = 0; i < NRTAP; ++i) f[i] = 0.0f;

    // ---- x prefetch registers (threads 0..63; row = sl*16 + tl) ----
    float xr6[6];
    if (tid < 64) {
        int t = tid & 15;                    // batch 0
        int tt = (t < NTIME) ? t : NTIME - 1;
        const float* xp = &x[((size_t)tt * 800 + s0 + (tid >> 4)) * 6];
#pragma unroll
        for (int c = 0; c < 6; ++c) xr6[c] = xp[c];
    }

    for (int b = 0; b < NBAT; ++b) {
        int t0 = b * TB;
        int nst = NTIME - t0; if (nst > TB) nst = TB;

        // w1 slice loads (global, L2-hot; in flight across stage + barrier)
        float4 wA[6], wB[6];
#pragma unroll
        for (int c = 0; c < 6; ++c) {
            wA[c] = *(const float4*)&w1T[c * 256 + j0];
            wB[c] = *(const float4*)&w1T[c * 256 + j0 + 4];
        }

        // ---- stage: xr6 -> xt + snow-fraction scalars ----
        if (tid < 64) {
            int tl = tid & 15;
            bool ok = (t0 + tl) < NTIME;
            float P = xr6[0], E = xr6[1], T1 = xr6[2], T2 = xr6[3];
#pragma unroll
            for (int c = 0; c < 6; ++c) xt[tid][c] = xr6[c];
            float den = T2 - T1;
            float cf = (T1 + T2) / ((den == 0.0f) ? 1.0f : den);
            cf = fminf(fmaxf(cf, -0.999999f), 0.999999f);
            float vf = acosf(cf) * (1.0f / 3.1415f);
            vf = (T1 >= 0.0f) ? 0.0f : vf;
            vf = (T2 <= 0.0f) ? 1.0f : vf;
            pls[tid] = ok ? P * (1.0f - vf) : 0.0f;
            evs[tid] = ok ? E : 0.0f;
            psv[tid] = ok ? P * vf : 0.0f;
        }
        __syncthreads();   // B1: xt ready

        // prefetch x for next batch (latency hidden under L1+GEMM+scan)
        if (b + 1 < NBAT && tid < 64) {
            int t = (b + 1) * TB + (tid & 15);
            int tt = (t < NTIME) ? t : NTIME - 1;
            const float* xp = &x[((size_t)tt * 800 + s0 + (tid >> 4)) * 6];
#pragma unroll
            for (int c = 0; c < 6; ++c) xr6[c] = xp[c];
        }

        // ---- L1: 4 rows x 8 k-elems -> swizzled Ah ----
#pragma unroll
        for (int rr = 0; rr < 4; ++rr) {
            int r = r0 + rr;
            float a[8];
            a[0] = bcv[0]; a[1] = bcv[1]; a[2] = bcv[2]; a[3] = bcv[3];
            a[4] = bcv[4]; a[5] = bcv[5]; a[6] = bcv[6]; a[7] = bcv[7];
#pragma unroll
            for (int c = 0; c < 6; ++c) {
                float xv = xt[r][c];
                a[0] = fmaf(xv, wA[c].x, a[0]);
                a[1] = fmaf(xv, wA[c].y, a[1]);
                a[2] = fmaf(xv, wA[c].z, a[2]);
                a[3] = fmaf(xv, wA[c].w, a[3]);
                a[4] = fmaf(xv, wB[c].x, a[4]);
                a[5] = fmaf(xv, wB[c].y, a[5]);
                a[6] = fmaf(xv, wB[c].z, a[6]);
                a[7] = fmaf(xv, wB[c].w, a[7]);
            }
            f16x8 hv;
#pragma unroll
            for (int e = 0; e < 8; ++e) hv[e] = (_Float16)tanh_fast(a[e]);
            Ah[ah_swz(jg, r)] = hv;
        }
        __syncthreads();   // B2: Ah ready

        // ---- GEMM: 96 MFMA, B from persistent registers, no barriers ----
        f32x4 acc[4][3];
#pragma unroll
        for (int nf = 0; nf < 3; ++nf) {
            float bb = bbias[nf];
#pragma unroll
            for (int mf = 0; mf < 4; ++mf) acc[mf][nf] = (f32x4){bb, bb, bb, bb};
        }
#pragma unroll
        for (int ks = 0; ks < 8; ++ks) {
            f16x8 af[4];
#pragma unroll
            for (int mf = 0; mf < 4; ++mf)
                af[mf] = Ah[ah_swz(ks * 4 + l4, mf * 16 + l15)];
#pragma unroll
            for (int mf = 0; mf < 4; ++mf)
#pragma unroll
                for (int nf = 0; nf < 3; ++nf)
                    acc[mf][nf] = __builtin_amdgcn_mfma_f32_16x16x32_f16(
                        af[mf], bfk[ks][nf], acc[mf][nf], 0, 0, 0);
        }

        // ---- epilogue: activations + forcing folding -> sio ----
#pragma unroll
        for (int mf = 0; mf < 4; ++mf) {
#pragma unroll
            for (int nf = 0; nf < 3; ++nf) {
                int colg = n0w + nf * 16 + l15;
                int ch = colg >> 7, cl = colg & 127;
#pragma unroll
                for (int rr = 0; rr < 4; ++rr) {
                    int r = mf * 16 + l4 * 4 + rr;
                    float v = acc[mf][nf][rr];
                    float o;
                    if (ch == 0)
                        o = pls[r] * fminf(fmaxf(v * (1.0f / 3.0f) + 0.5f, 0.0f), 1.0f);
                    else if (ch == 1)
                        o = evs[r] * fmaxf(v, 0.0f) * 2.0f;
                    else
                        o = fminf(__expf(v), 60000.0f);
                    sio[ch][r][cl] = (_Float16)o;
                }
            }
        }
        __syncthreads();   // B3: sio ready

        // ---- scan: 16 steps, all 512 threads; reductions batched after ----
        float cs[TB];
#pragma unroll
        for (int t = 0; t < TB; ++t) {
            cs[t] = 0.0f;
            if (t < nst) {
                int r = sl * 16 + t;
                float pl = (float)sio[0][r][hc];
                float ev = (float)sio[1][r][hc];
                float vm = (float)sio[2][r][hc];
                float ps = psv[r];

                float x1 = Sf + ps;
                float qf = fminf(x1, vm);
                Sf = fmaxf(x1 - vm, 0.0f);
                float H  = fmaxf(Ss + pl + qf - ev, 0.0f);
                float qp = fmaxf(kp * (H - gL), 0.0f);
                float mh = fminf(H, gL);
                float qs = ksP * mh;
                Ss = H - qp - qs;
                float qg = fmaf(kgP, fmaf(qs, gp, Sg), qb);
                Sg = Sg - qg;
                float qt = qp + kq * mh + qg;

#pragma unroll
                for (int j = 0; j < NRTAP; ++j) f[j] = fmaf(wr[j], qt, f[j]);
                cs[t] = f[0];
#pragma unroll
                for (int j = 0; j < NRTAP - 1; ++j) f[j] = f[j + 1];
                f[NRTAP - 1] = 0.0f;
            }
        }
        // 16 independent wave reductions (shfl latency overlapped)
#pragma unroll
        for (int t = 0; t < TB; ++t) {
            float c = cs[t];
#pragma unroll
            for (int off = 32; off; off >>= 1) c += __shfl_xor(c, off);
            cs[t] = c;
        }
        if (lane == 0) {
#pragma unroll
            for (int t = 0; t < TB; ++t) part[wid][t] = cs[t];
        }
        __syncthreads();   // B4: partials ready, sio/xt free

        if (tid < 64) {
            int osl = tid >> 4, t = tid & 15;
            if (t < nst)
                out[(size_t)(t0 + t) * 800 + s0 + osl] =
                    part[osl * 2][t] + part[osl * 2 + 1][t];
        }
    }
}

// ---------------------------------------------------------------------------
extern "C" void kernel_launch(void* const* d_in, const int* in_sizes, int n_in,
                              void* d_out, int out_size, void* d_ws, size_t ws_size,
                              hipStream_t stream)
{
    const float* x      = (const float*)d_in[0];
    const float* xc     = (const float*)d_in[1];
    const float* fcW1_w = (const float*)d_in[2];
    const float* fcW1_b = (const float*)d_in[3];
    const float* fcW2_w = (const float*)d_in[4];
    const float* fcW2_b = (const float*)d_in[5];
    const float* fcT1_w = (const float*)d_in[6];
    const float* fcT1_b = (const float*)d_in[7];
    const float* fcT2_w = (const float*)d_in[8];
    const float* fcT2_b = (const float*)d_in[9];
    const float* fcR1_w = (const float*)d_in[10];
    const float* fcR1_b = (const float*)d_in[11];
    const float* fcR2_w = (const float*)d_in[12];
    const float* fcR2_b = (const float*)d_in[13];
    float* out = (float*)d_out;

    char* wsb = (char*)d_ws;
    size_t off = 0;
    float* params = (float*)(wsb + off); off += (size_t)7 * NSH * 4;
    float* rbuf   = (float*)(wsb + off); off += (size_t)NRTAP * NSH * 4;
    float* basec  = (float*)(wsb + off); off += 800 * 256 * 4;
    float* h1w    = (float*)(wsb + off); off += 800 * 256 * 4;
    float* h1r    = (float*)(wsb + off); off += 800 * 256 * 4;
    _Float16* w2s = (_Float16*)(wsb + off); off += 98304 * 2;

    k_prep_w2h<<<384, 256, 0, stream>>>(fcT2_w, w2s);
    k_site_l1<<<800, 256, 0, stream>>>(xc, fcW1_w, fcW1_b, fcR1_w, fcR1_b,
                                       fcT1_w, fcT1_b, h1w, h1r, basec);
    k_whead<<<dim3(100, 7), 128, 0, stream>>>(h1w, fcW2_w, fcW2_b, params);
    k_softmax_ga<<<800, 128, 0, stream>>>(params + (size_t)6 * NSH);
    k_rhead<<<dim3(100, 15), 128, 0, stream>>>(h1r, fcR2_w, fcR2_b, rbuf);

    k_fused3<<<NSITE / SPB, 512, 0, stream>>>(
        x, fcT1_w, basec, (const f16x8*)w2s, fcT2_b, params, rbuf, out);
}

// Round 10
// 774.526 us; speedup vs baseline: 1.2996x; 1.2972x over previous
//
#include <hip/hip_runtime.h>
#include <cmath>

// WaterNet: NH=128, NG=32, NR=15, NT=730, NS=800
#define NHID 128
#define NSITE 800
#define NTIME 730
#define NRTAP 15
constexpr int NSH = NSITE * NHID;  // 102400

typedef _Float16 f16x8 __attribute__((ext_vector_type(8)));
typedef float f32x4 __attribute__((ext_vector_type(4)));

__device__ __forceinline__ float tanh_fast(float x) {
    float e = __expf(2.0f * x);
    return 1.0f - 2.0f / (e + 1.0f);
}
__device__ __forceinline__ float sigmoid_fast(float x) {
    return 1.0f / (1.0f + __expf(-x));
}
__device__ __forceinline__ unsigned short h_bits(_Float16 h) {
    union { _Float16 h; unsigned short u; } c; c.h = h; return c.u;
}
__device__ __forceinline__ float h_val(unsigned short u) {
    union { unsigned short u; _Float16 h; } c; c.u = u; return (float)c.h;
}
// Swizzled index into A-fragment LDS tile: jg = k-octet (0..31), r = row (0..63).
// Conflict-free for L1 write and MFMA read (verified r7: SQ_LDS_BANK_CONFLICT = 0).
__device__ __forceinline__ int ah_swz(int jg, int r) {
    return jg * 64 + ((r & ~7) | ((r ^ jg) & 7));
}

// ---------------------------------------------------------------------------
// P0: fcT2_w (fp32 [256][384]) -> fp16 MFMA layout w2s[K0][kg][col][e]
// ---------------------------------------------------------------------------
__global__ void k_prep_w2h(const float* __restrict__ w2, _Float16* __restrict__ w2s)
{
    int idx = blockIdx.x * 256 + threadIdx.x;
    if (idx >= 98304) return;
    int k = idx / 384, col = idx - k * 384;
    int K0 = k >> 5, kg = (k >> 3) & 3, e = k & 7;
    w2s[(size_t)K0 * 12288 + kg * 3072 + col * 8 + e] = (_Float16)w2[(size_t)k * 384 + col];
}

// ---------------------------------------------------------------------------
// A1: per-site layer-1 for all three heads.
// ---------------------------------------------------------------------------
__global__ void k_site_l1(const float* __restrict__ xc,
                          const float* __restrict__ w1W, const float* __restrict__ b1W,
                          const float* __restrict__ w1R, const float* __restrict__ b1R,
                          const float* __restrict__ w1T, const float* __restrict__ b1T,
                          float* __restrict__ h1w, float* __restrict__ h1r,
                          float* __restrict__ basec)
{
    __shared__ float xr[32];
    int s = blockIdx.x, j = threadIdx.x;
    if (j < 32) xr[j] = xc[s * 32 + j];
    __syncthreads();
    float aW = b1W[j], aR = b1R[j], aT = b1T[j];
#pragma unroll 8
    for (int k = 0; k < 32; ++k) {
        float xv = xr[k];
        aW = fmaf(xv, w1W[k * 256 + j], aW);
        aR = fmaf(xv, w1R[k * 256 + j], aR);
        aT = fmaf(xv, w1T[(6 + k) * 256 + j], aT);
    }
    h1w[s * 256 + j]   = tanh_fast(aW);
    h1r[s * 256 + j]   = tanh_fast(aR);
    basec[s * 256 + j] = aT;
}

// ---------------------------------------------------------------------------
// A2: static parameter head layer-2 + activations.
// ---------------------------------------------------------------------------
__global__ void k_whead(const float* __restrict__ h1w,
                        const float* __restrict__ w2, const float* __restrict__ b2,
                        float* __restrict__ params)
{
    __shared__ float h[8 * 256];
    int sBase = blockIdx.x * 8, g = blockIdx.y, tid = threadIdx.x;
    for (int p = tid; p < 2048; p += 128) h[p] = h1w[sBase * 256 + p];
    __syncthreads();
    float bias = b2[g * 128 + tid];
    float acc[8];
#pragma unroll
    for (int i = 0; i < 8; ++i) acc[i] = bias;
    for (int k = 0; k < 256; ++k) {
        float wv = w2[k * 896 + g * 128 + tid];
#pragma unroll
        for (int i = 0; i < 8; ++i) acc[i] = fmaf(h[i * 256 + k], wv, acc[i]);
    }
#pragma unroll
    for (int i = 0; i < 8; ++i) {
        float v = acc[i], o;
        if (g == 0 || g == 1 || g == 3)  o = sigmoid_fast(v);
        else if (g == 2)                 o = sigmoid_fast(v) * 0.1f;
        else if (g == 4)                 o = __expf(v) * 2.0f;
        else if (g == 5)                 o = fmaxf(v, 0.0f);
        else                             o = v;
        params[g * NSH + (sBase + i) * 128 + tid] = o;
    }
}

// ---------------------------------------------------------------------------
// A3: softmax of ga over 128 buckets, in place.
// ---------------------------------------------------------------------------
__global__ void k_softmax_ga(float* __restrict__ ga)
{
    int s = blockIdx.x, h = threadIdx.x;
    float v = ga[s * 128 + h];
    float m = v;
#pragma unroll
    for (int off = 32; off; off >>= 1) m = fmaxf(m, __shfl_xor(m, off));
    __shared__ float ra[2], rb[2];
    if ((h & 63) == 0) ra[h >> 6] = m;
    __syncthreads();
    m = fmaxf(ra[0], ra[1]);
    float e = __expf(v - m);
    float t = e;
#pragma unroll
    for (int off = 32; off; off >>= 1) t += __shfl_xor(t, off);
    if ((h & 63) == 0) rb[h >> 6] = t;
    __syncthreads();
    ga[s * 128 + h] = e / (rb[0] + rb[1]);
}

// ---------------------------------------------------------------------------
// A4: routing head layer-2, relu, [NRTAP][NSITE*NHID]
// ---------------------------------------------------------------------------
__global__ void k_rhead(const float* __restrict__ h1r,
                        const float* __restrict__ w2, const float* __restrict__ b2,
                        float* __restrict__ rbuf)
{
    __shared__ float h[8 * 256];
    int sBase = blockIdx.x * 8, g = blockIdx.y, tid = threadIdx.x;
    for (int p = tid; p < 2048; p += 128) h[p] = h1r[sBase * 256 + p];
    __syncthreads();
    int c = g * 128 + tid;
    float bias = b2[c];
    float acc[8];
#pragma unroll
    for (int i = 0; i < 8; ++i) acc[i] = bias;
    for (int k = 0; k < 256; ++k) {
        float wv = w2[k * 1920 + c];
#pragma unroll
        for (int i = 0; i < 8; ++i) acc[i] = fmaf(h[i * 256 + k], wv, acc[i]);
    }
    int hh = c / 15, ii = c - hh * 15;
#pragma unroll
    for (int i = 0; i < 8; ++i)
        rbuf[ii * NSH + (sBase + i) * 128 + hh] = fmaxf(acc[i], 0.0f);
}

// ---------------------------------------------------------------------------
// COMBO3 = r7's combo2 with the Ah/sio LDS UNION (52,992 B -> 2 blocks/CU,
// double r7's residency). Ah (GEMM A-frags) and sio (epilogue transpose) are
// never live at the same time; one extra barrier separates them.
// sio is channel-interleaved u16[64][132][3] -> bank-friendly for both the
// scattered epilogue writes and the contiguous 6B pack-phase reads.
// ---------------------------------------------------------------------------
struct ThSm {
    union U {
        f16x8 Ah[2048];                   // 32 KB (phase: L1 + GEMM)
        unsigned short sio[64][132][3];   // 50688 B (phase: epilogue + pack)
    } u;
    float xt[64][6];
    float pls[64], evs[64], psv[64];
};                                        // total 52,992 B

__global__ __launch_bounds__(512, 1) void k_combo3(
    const float* __restrict__ x, const float* __restrict__ w1T,
    const float* __restrict__ basec, const f16x8* __restrict__ w2B,
    const float* __restrict__ b2,
    const float* __restrict__ params, const float* __restrict__ rbuf,
    float* __restrict__ state, float* __restrict__ fut, float* __restrict__ out,
    unsigned* __restrict__ PEw, unsigned short* __restrict__ VMw,
    float* __restrict__ PSw, int t0h, int rowsH,
    const unsigned* __restrict__ PEr, const unsigned short* __restrict__ VMr,
    const float* __restrict__ PSr, int t0s, int Tcs, int isFirst, int nScan)
{
    __shared__ __align__(16) char smem[sizeof(ThSm)];
    int tid = threadIdx.x;

    if ((int)blockIdx.x < nScan) {
        // ===================== SCAN (chunk c-1) =====================
        float* part = (float*)smem;                 // [8][368] = 11776 B
        int sl = tid >> 7, hc = tid & 127;
        int lane = tid & 63, wid = tid >> 6;
        int site = blockIdx.x * 4 + sl;
        int cell = site * 128 + hc;

        float kp  = params[0 * NSH + cell];
        float ksP = params[1 * NSH + cell];
        float kgP = params[2 * NSH + cell];
        float gp  = params[3 * NSH + cell];
        float gL  = params[4 * NSH + cell];
        float qb  = params[5 * NSH + cell];
        float ga  = params[6 * NSH + cell];
        float kq  = ksP * (1.0f - gp);

        float wr[NRTAP];
#pragma unroll
        for (int i = 0; i < NRTAP; ++i) wr[i] = ga * rbuf[i * NSH + cell];

        float Sf, Ss, Sg, f[NRTAP];
        if (isFirst) {
            Sf = Ss = Sg = 0.0f;
#pragma unroll
            for (int i = 0; i < NRTAP; ++i) f[i] = 0.0f;
        } else {
            Sf = state[cell];
            Ss = state[NSH + cell];
            Sg = state[2 * NSH + cell];
#pragma unroll
            for (int i = 0; i < NRTAP; ++i) f[i] = fut[i * NSH + cell];
        }

        const unsigned* pep = PEr + cell;
        const unsigned short* vmp = VMr + cell;

#define LD_T(PE_, VM_, PS_, T_) { int t_ = (T_); bool ok_ = t_ < Tcs;          \
        PE_ = ok_ ? pep[(size_t)t_ * NSH] : 0u;                                \
        VM_ = ok_ ? vmp[(size_t)t_ * NSH] : (unsigned short)0;                 \
        PS_ = ok_ ? PSr[(size_t)t_ * 800 + site] : 0.0f; }

        unsigned peA[4], peB[4], peC[4], peD[4];
        unsigned short vmA[4], vmB[4], vmC[4], vmD[4];
        float psA[4], psB[4], psC[4], psD[4];
#pragma unroll
        for (int i = 0; i < 4; ++i) LD_T(peA[i], vmA[i], psA[i], i)
#pragma unroll
        for (int i = 0; i < 4; ++i) LD_T(peB[i], vmB[i], psB[i], 4 + i)
#pragma unroll
        for (int i = 0; i < 4; ++i) LD_T(peC[i], vmC[i], psC[i], 8 + i)
#pragma unroll
        for (int i = 0; i < 4; ++i) LD_T(peD[i], vmD[i], psD[i], 12 + i)

        int ngroups = (Tcs + 3) >> 2;
        for (int g = 0; g < ngroups; ++g) {
            int tb = g * 4;
            unsigned peE[4]; unsigned short vmE[4]; float psE[4];
#pragma unroll
            for (int i = 0; i < 4; ++i) LD_T(peE[i], vmE[i], psE[i], tb + 16 + i)

            float cs[4];
#pragma unroll
            for (int i = 0; i < 4; ++i) {
                cs[i] = 0.0f;
                if (tb + i < Tcs) {
                    float pl = h_val((unsigned short)(peA[i] & 0xffffu));
                    float ev = h_val((unsigned short)(peA[i] >> 16));
                    float vm = h_val(vmA[i]);
                    float ps = psA[i];

                    float x1 = Sf + ps;
                    float qf = fminf(x1, vm);
                    Sf = fmaxf(x1 - vm, 0.0f);
                    float H  = fmaxf(Ss + pl + qf - ev, 0.0f);
                    float qp = fmaxf(kp * (H - gL), 0.0f);
                    float mh = fminf(H, gL);
                    float qs = ksP * mh;
                    Ss = H - qp - qs;
                    float qg = fmaf(kgP, fmaf(qs, gp, Sg), qb);
                    Sg = Sg - qg;
                    float qt = qp + kq * mh + qg;
#pragma unroll
                    for (int j = 0; j < NRTAP; ++j) f[j] = fmaf(wr[j], qt, f[j]);
                    cs[i] = f[0];
#pragma unroll
                    for (int j = 0; j < NRTAP - 1; ++j) f[j] = f[j + 1];
                    f[NRTAP - 1] = 0.0f;
                }
            }
#pragma unroll
            for (int i = 0; i < 4; ++i) {
                float c = cs[i];
#pragma unroll
                for (int off = 32; off; off >>= 1) c += __shfl_xor(c, off);
                cs[i] = c;
            }
            if (lane == 0) {
#pragma unroll
                for (int i = 0; i < 4; ++i)
                    if (tb + i < Tcs) part[wid * 368 + tb + i] = cs[i];
            }
#pragma unroll
            for (int i = 0; i < 4; ++i) {
                peA[i] = peB[i]; peB[i] = peC[i]; peC[i] = peD[i]; peD[i] = peE[i];
                vmA[i] = vmB[i]; vmB[i] = vmC[i]; vmC[i] = vmD[i]; vmD[i] = vmE[i];
                psA[i] = psB[i]; psB[i] = psC[i]; psC[i] = psD[i]; psD[i] = psE[i];
            }
        }
#undef LD_T

        state[cell]           = Sf;
        state[NSH + cell]     = Ss;
        state[2 * NSH + cell] = Sg;
#pragma unroll
        for (int i = 0; i < NRTAP; ++i) fut[i * NSH + cell] = f[i];

        __syncthreads();
        {
            int sl2 = tid >> 7, tl = tid & 127;
            for (int t = tl; t < Tcs; t += 128)
                out[(size_t)(t0s + t) * 800 + blockIdx.x * 4 + sl2] =
                    part[(sl2 * 2) * 368 + t] + part[(sl2 * 2 + 1) * 368 + t];
        }
        return;
    }

    // ===================== TIMEHEAD tile (chunk c) =====================
    ThSm* sm = (ThSm*)smem;
    int m0 = ((int)blockIdx.x - nScan) * 64;
    int wid = tid >> 6, lane = tid & 63;
    int l15 = lane & 15, l4 = lane >> 4;
    int n0w = wid * 48;

    // preload B fragments for this wave's 48 cols (compiler schedules the
    // loads early / sinks into the k-loop; L2-hot; no spill at VGPR ~92)
    f16x8 bfk[8][3];
#pragma unroll
    for (int ks = 0; ks < 8; ++ks)
#pragma unroll
        for (int nf = 0; nf < 3; ++nf)
            bfk[ks][nf] = w2B[(size_t)ks * 1536 + l4 * 384 + n0w + nf * 16 + l15];

    if (tid < 64) {
        int row = m0 + tid;
        const float* xp = &x[((size_t)t0h * 800 + row) * 6];
        float P = xp[0], E = xp[1], T1 = xp[2], T2 = xp[3];
        sm->xt[tid][0] = P;  sm->xt[tid][1] = E;     sm->xt[tid][2] = T1;
        sm->xt[tid][3] = T2; sm->xt[tid][4] = xp[4]; sm->xt[tid][5] = xp[5];
        float den = T2 - T1;
        float cf = (T1 + T2) / ((den == 0.0f) ? 1.0f : den);
        cf = fminf(fmaxf(cf, -0.999999f), 0.999999f);
        float vf = acosf(cf) * (1.0f / 3.1415f);
        vf = (T1 >= 0.0f) ? 0.0f : vf;
        vf = (T2 <= 0.0f) ? 1.0f : vf;
        sm->pls[tid] = P * (1.0f - vf);
        sm->evs[tid] = E;
        sm->psv[tid] = P * vf;
        PSw[row] = P * vf;
    }
    __syncthreads();   // B1: xt ready

    // ---- L1: thread = (k-octet jg, row-quad rg) -> swizzled Ah ----
    {
        int jg = tid & 31, rg = tid >> 5;
        int j0 = jg * 8;
        float w1c[6][8];
#pragma unroll
        for (int c = 0; c < 6; ++c) {
            float4 lo = *(const float4*)&w1T[c * 256 + j0];
            float4 hi = *(const float4*)&w1T[c * 256 + j0 + 4];
            w1c[c][0] = lo.x; w1c[c][1] = lo.y; w1c[c][2] = lo.z; w1c[c][3] = lo.w;
            w1c[c][4] = hi.x; w1c[c][5] = hi.y; w1c[c][6] = hi.z; w1c[c][7] = hi.w;
        }
#pragma unroll
        for (int rr = 0; rr < 4; ++rr) {
            int r = rg * 4 + rr;
            int srow = (m0 + r) % 800;
            const float* bp = &basec[(size_t)srow * 256 + j0];
            float4 b0 = *(const float4*)bp;
            float4 b1 = *(const float4*)(bp + 4);
            float a[8] = {b0.x, b0.y, b0.z, b0.w, b1.x, b1.y, b1.z, b1.w};
#pragma unroll
            for (int c = 0; c < 6; ++c) {
                float xv = sm->xt[r][c];
#pragma unroll
                for (int e = 0; e < 8; ++e) a[e] = fmaf(xv, w1c[c][e], a[e]);
            }
            f16x8 hv;
#pragma unroll
            for (int e = 0; e < 8; ++e) hv[e] = (_Float16)tanh_fast(a[e]);
            sm->u.Ah[ah_swz(jg, r)] = hv;
        }
    }
    __syncthreads();   // B2: Ah ready

    // ---- GEMM: 96 MFMAs, A from LDS, B from registers ----
    f32x4 acc[4][3];
#pragma unroll
    for (int nf = 0; nf < 3; ++nf) {
        float bb = b2[n0w + nf * 16 + l15];
#pragma unroll
        for (int mf = 0; mf < 4; ++mf) acc[mf][nf] = (f32x4){bb, bb, bb, bb};
    }
#pragma unroll
    for (int ks = 0; ks < 8; ++ks) {
        f16x8 af[4];
#pragma unroll
        for (int mf = 0; mf < 4; ++mf)
            af[mf] = sm->u.Ah[ah_swz(ks * 4 + l4, mf * 16 + l15)];
#pragma unroll
        for (int mf = 0; mf < 4; ++mf)
#pragma unroll
            for (int nf = 0; nf < 3; ++nf)
                acc[mf][nf] = __builtin_amdgcn_mfma_f32_16x16x32_f16(
                    af[mf], bfk[ks][nf], acc[mf][nf], 0, 0, 0);
    }
    __syncthreads();   // B2b: ALL waves done reading Ah -> sio may overwrite

    // ---- epilogue: activations -> interleaved sio (union over Ah) ----
#pragma unroll
    for (int mf = 0; mf < 4; ++mf) {
#pragma unroll
        for (int nf = 0; nf < 3; ++nf) {
            int colg = n0w + nf * 16 + l15;
            int ch = colg >> 7, cl = colg & 127;
#pragma unroll
            for (int rr = 0; rr < 4; ++rr) {
                int r = mf * 16 + l4 * 4 + rr;
                float v = acc[mf][nf][rr];
                float o;
                if (ch == 0)
                    o = sm->pls[r] * fminf(fmaxf(v * (1.0f / 3.0f) + 0.5f, 0.0f), 1.0f);
                else if (ch == 1)
                    o = sm->evs[r] * fmaxf(v, 0.0f) * 2.0f;
                else
                    o = fminf(__expf(v), 60000.0f);
                sm->u.sio[r][cl][ch] = h_bits((_Float16)o);
            }
        }
    }
    __syncthreads();   // B3: sio ready

    // ---- pack + coalesced store: u32 {pl,ev} + u16 {vm} per cell ----
#pragma unroll
    for (int i = 0; i < 16; ++i) {
        int cidx = tid + i * 512;            // 0..8191
        int r = cidx >> 7, c2 = cidx & 127;
        unsigned pe = (unsigned)sm->u.sio[r][c2][0]
                    | ((unsigned)sm->u.sio[r][c2][1] << 16);
        unsigned short vmb = sm->u.sio[r][c2][2];
        size_t gidx = (size_t)(m0 + r) * 128 + c2;
        PEw[gidx] = pe;
        VMw[gidx] = vmb;
    }
}

// ---------------------------------------------------------------------------
extern "C" void kernel_launch(void* const* d_in, const int* in_sizes, int n_in,
                              void* d_out, int out_size, void* d_ws, size_t ws_size,
                              hipStream_t stream)
{
    const float* x      = (const float*)d_in[0];
    const float* xc     = (const float*)d_in[1];
    const float* fcW1_w = (const float*)d_in[2];
    const float* fcW1_b = (const float*)d_in[3];
    const float* fcW2_w = (const float*)d_in[4];
    const float* fcW2_b = (const float*)d_in[5];
    const float* fcT1_w = (const float*)d_in[6];
    const float* fcT1_b = (const float*)d_in[7];
    const float* fcT2_w = (const float*)d_in[8];
    const float* fcT2_b = (const float*)d_in[9];
    const float* fcR1_w = (const float*)d_in[10];
    const float* fcR1_b = (const float*)d_in[11];
    const float* fcR2_w = (const float*)d_in[12];
    const float* fcR2_b = (const float*)d_in[13];
    float* out = (float*)d_out;

    char* wsb = (char*)d_ws;
    size_t off = 0;
    float* params = (float*)(wsb + off); off += (size_t)7 * NSH * 4;
    float* rbuf   = (float*)(wsb + off); off += (size_t)NRTAP * NSH * 4;
    float* basec  = (float*)(wsb + off); off += 800 * 256 * 4;
    float* h1w    = (float*)(wsb + off); off += 800 * 256 * 4;
    float* h1r    = (float*)(wsb + off); off += 800 * 256 * 4;
    float* state  = (float*)(wsb + off); off += (size_t)3 * NSH * 4;
    float* fut    = (float*)(wsb + off); off += (size_t)NRTAP * NSH * 4;
    _Float16* w2s = (_Float16*)(wsb + off); off += 98304 * 2;
    size_t fixedB = off;

    // per-timestep bytes in one chunk buffer: PE(4) + VM(2) per cell + PS row
    const size_t perT = (size_t)NSH * 6 + 800 * 4;
    long avail = (long)ws_size - (long)fixedB - 4096;
    int Tc = (int)(avail / (long)(2 * perT));
    if (Tc > 366) Tc = 366;
    Tc &= ~1;
    if (Tc < 2) Tc = 2;

    unsigned*       PE0 = (unsigned*)(wsb + off);       off += (size_t)Tc * NSH * 4;
    unsigned short* VM0 = (unsigned short*)(wsb + off); off += (size_t)Tc * NSH * 2;
    float*          PS0 = (float*)(wsb + off);          off += (size_t)Tc * 800 * 4;
    unsigned*       PE1 = (unsigned*)(wsb + off);       off += (size_t)Tc * NSH * 4;
    unsigned short* VM1 = (unsigned short*)(wsb + off); off += (size_t)Tc * NSH * 2;
    float*          PS1 = (float*)(wsb + off);          off += (size_t)Tc * 800 * 4;

    k_prep_w2h<<<384, 256, 0, stream>>>(fcT2_w, w2s);
    k_site_l1<<<800, 256, 0, stream>>>(xc, fcW1_w, fcW1_b, fcR1_w, fcR1_b,
                                       fcT1_w, fcT1_b, h1w, h1r, basec);
    k_whead<<<dim3(100, 7), 128, 0, stream>>>(h1w, fcW2_w, fcW2_b, params);
    k_softmax_ga<<<800, 128, 0, stream>>>(params + (size_t)6 * NSH);
    k_rhead<<<dim3(100, 15), 128, 0, stream>>>(h1r, fcR2_w, fcR2_b, rbuf);

    int nch = (NTIME + Tc - 1) / Tc;
    for (int c = 0; c <= nch; ++c) {
        int nScan = (c > 0) ? 200 : 0;
        int Tch = 0;
        if (c < nch) { Tch = NTIME - c * Tc; if (Tch > Tc) Tch = Tc; }
        int rowsH = Tch * 800;
        int thB = rowsH / 64;
        int grid = nScan + thB;
        if (grid == 0) continue;
        int t0s = (c - 1) * Tc;
        int Tcs = 0;
        if (c > 0) { Tcs = NTIME - t0s; if (Tcs > Tc) Tcs = Tc; }
        unsigned*       PEw = (c & 1) ? PE1 : PE0;
        unsigned short* VMw = (c & 1) ? VM1 : VM0;
        float*          PSw = (c & 1) ? PS1 : PS0;
        const unsigned*       PEr = ((c - 1) & 1) ? PE1 : PE0;
        const unsigned short* VMr = ((c - 1) & 1) ? VM1 : VM0;
        const float*          PSr = ((c - 1) & 1) ? PS1 : PS0;
        k_combo3<<<grid, 512, 0, stream>>>(
            x, fcT1_w, basec, (const f16x8*)w2s, fcT2_b, params, rbuf,
            state, fut, out,
            PEw, VMw, PSw, c * Tc, rowsH,
            PEr, VMr, PSr, t0s, Tcs, (c == 1) ? 1 : 0, nScan);
    }
}

// Round 11
// 482.073 us; speedup vs baseline: 2.0880x; 1.6067x over previous
//
#include <hip/hip_runtime.h>
#include <cmath>

// WaterNet: NH=128, NG=32, NR=15, NT=730, NS=800
#define NHID 128
#define NSITE 800
#define NTIME 730
#define NRTAP 15
constexpr int NSH = NSITE * NHID;  // 102400

typedef _Float16 f16x8 __attribute__((ext_vector_type(8)));
typedef float f32x4 __attribute__((ext_vector_type(4)));

__device__ __forceinline__ float tanh_fast(float x) {
    float e = __expf(2.0f * x);
    return 1.0f - 2.0f / (e + 1.0f);
}
__device__ __forceinline__ float sigmoid_fast(float x) {
    return 1.0f / (1.0f + __expf(-x));
}
__device__ __forceinline__ unsigned short h_bits(_Float16 h) {
    union { _Float16 h; unsigned short u; } c; c.h = h; return c.u;
}
__device__ __forceinline__ float h_val(unsigned short u) {
    union { unsigned short u; _Float16 h; } c; c.u = u; return (float)c.h;
}
// Swizzled index into 32-row A-fragment LDS tile: jg = k-octet (0..31), r = row (0..31).
// Conflict-free for L1 write and MFMA read (same scheme verified r7: 0 conflicts).
__device__ __forceinline__ int ah_swz32(int jg, int r) {
    return jg * 32 + ((r & ~7) | ((r ^ jg) & 7));
}

// ---------------------------------------------------------------------------
// P0: fcT2_w (fp32 [256][384]) -> fp16 MFMA layout w2s[K0][kg][col][e]
// ---------------------------------------------------------------------------
__global__ void k_prep_w2h(const float* __restrict__ w2, _Float16* __restrict__ w2s)
{
    int idx = blockIdx.x * 256 + threadIdx.x;
    if (idx >= 98304) return;
    int k = idx / 384, col = idx - k * 384;
    int K0 = k >> 5, kg = (k >> 3) & 3, e = k & 7;
    w2s[(size_t)K0 * 12288 + kg * 3072 + col * 8 + e] = (_Float16)w2[(size_t)k * 384 + col];
}

// ---------------------------------------------------------------------------
// A1: per-site layer-1 for all three heads.
// ---------------------------------------------------------------------------
__global__ void k_site_l1(const float* __restrict__ xc,
                          const float* __restrict__ w1W, const float* __restrict__ b1W,
                          const float* __restrict__ w1R, const float* __restrict__ b1R,
                          const float* __restrict__ w1T, const float* __restrict__ b1T,
                          float* __restrict__ h1w, float* __restrict__ h1r,
                          float* __restrict__ basec)
{
    __shared__ float xr[32];
    int s = blockIdx.x, j = threadIdx.x;
    if (j < 32) xr[j] = xc[s * 32 + j];
    __syncthreads();
    float aW = b1W[j], aR = b1R[j], aT = b1T[j];
#pragma unroll 8
    for (int k = 0; k < 32; ++k) {
        float xv = xr[k];
        aW = fmaf(xv, w1W[k * 256 + j], aW);
        aR = fmaf(xv, w1R[k * 256 + j], aR);
        aT = fmaf(xv, w1T[(6 + k) * 256 + j], aT);
    }
    h1w[s * 256 + j]   = tanh_fast(aW);
    h1r[s * 256 + j]   = tanh_fast(aR);
    basec[s * 256 + j] = aT;
}

// ---------------------------------------------------------------------------
// A2: static parameter head layer-2 + activations.
// ---------------------------------------------------------------------------
__global__ void k_whead(const float* __restrict__ h1w,
                        const float* __restrict__ w2, const float* __restrict__ b2,
                        float* __restrict__ params)
{
    __shared__ float h[8 * 256];
    int sBase = blockIdx.x * 8, g = blockIdx.y, tid = threadIdx.x;
    for (int p = tid; p < 2048; p += 128) h[p] = h1w[sBase * 256 + p];
    __syncthreads();
    float bias = b2[g * 128 + tid];
    float acc[8];
#pragma unroll
    for (int i = 0; i < 8; ++i) acc[i] = bias;
    for (int k = 0; k < 256; ++k) {
        float wv = w2[k * 896 + g * 128 + tid];
#pragma unroll
        for (int i = 0; i < 8; ++i) acc[i] = fmaf(h[i * 256 + k], wv, acc[i]);
    }
#pragma unroll
    for (int i = 0; i < 8; ++i) {
        float v = acc[i], o;
        if (g == 0 || g == 1 || g == 3)  o = sigmoid_fast(v);
        else if (g == 2)                 o = sigmoid_fast(v) * 0.1f;
        else if (g == 4)                 o = __expf(v) * 2.0f;
        else if (g == 5)                 o = fmaxf(v, 0.0f);
        else                             o = v;
        params[g * NSH + (sBase + i) * 128 + tid] = o;
    }
}

// ---------------------------------------------------------------------------
// A3: softmax of ga over 128 buckets, in place.
// ---------------------------------------------------------------------------
__global__ void k_softmax_ga(float* __restrict__ ga)
{
    int s = blockIdx.x, h = threadIdx.x;
    float v = ga[s * 128 + h];
    float m = v;
#pragma unroll
    for (int off = 32; off; off >>= 1) m = fmaxf(m, __shfl_xor(m, off));
    __shared__ float ra[2], rb[2];
    if ((h & 63) == 0) ra[h >> 6] = m;
    __syncthreads();
    m = fmaxf(ra[0], ra[1]);
    float e = __expf(v - m);
    float t = e;
#pragma unroll
    for (int off = 32; off; off >>= 1) t += __shfl_xor(t, off);
    if ((h & 63) == 0) rb[h >> 6] = t;
    __syncthreads();
    ga[s * 128 + h] = e / (rb[0] + rb[1]);
}

// ---------------------------------------------------------------------------
// A4: routing head layer-2, relu, [NRTAP][NSITE*NHID]
// ---------------------------------------------------------------------------
__global__ void k_rhead(const float* __restrict__ h1r,
                        const float* __restrict__ w2, const float* __restrict__ b2,
                        float* __restrict__ rbuf)
{
    __shared__ float h[8 * 256];
    int sBase = blockIdx.x * 8, g = blockIdx.y, tid = threadIdx.x;
    for (int p = tid; p < 2048; p += 128) h[p] = h1r[sBase * 256 + p];
    __syncthreads();
    int c = g * 128 + tid;
    float bias = b2[c];
    float acc[8];
#pragma unroll
    for (int i = 0; i < 8; ++i) acc[i] = bias;
    for (int k = 0; k < 256; ++k) {
        float wv = w2[k * 1920 + c];
#pragma unroll
        for (int i = 0; i < 8; ++i) acc[i] = fmaf(h[i * 256 + k], wv, acc[i]);
    }
    int hh = c / 15, ii = c - hh * 15;
#pragma unroll
    for (int i = 0; i < 8; ++i)
        rbuf[ii * NSH + (sBase + i) * 128 + hh] = fmaxf(acc[i], 0.0f);
}

// ---------------------------------------------------------------------------
// COMBO4: 256-thread blocks.
//   blocks [0,nScan): barrier-free scan of chunk c-1 (2 sites/block);
//   blocks [nScan,..): timehead 32-row tiles of chunk c, channel-aligned
//   waves (wave w owns hidden cols w*32..+31 x all 3 channels) so each lane
//   holds pl/ev/vm of the SAME cell -> direct packed register stores, no
//   LDS transpose, 2 barriers, 17.5 KB LDS, ~100 VGPR -> 4-5 blocks/CU.
// ---------------------------------------------------------------------------
struct ThSm2 {
    f16x8 Ah[1024];                 // 16 KB swizzled A fragments (32 rows)
    float xt[32][6];
    float pls[32], evs[32], psv[32];
};                                  // 17,536 B

__global__ __launch_bounds__(256, 4) void k_combo4(
    const float* __restrict__ x, const float* __restrict__ w1T,
    const float* __restrict__ basec, const f16x8* __restrict__ w2B,
    const float* __restrict__ b2,
    const float* __restrict__ params, const float* __restrict__ rbuf,
    float* __restrict__ state, float* __restrict__ fut, float* __restrict__ out,
    unsigned* __restrict__ PEw, unsigned short* __restrict__ VMw,
    float* __restrict__ PSw, int t0h, int rowsH,
    const unsigned* __restrict__ PEr, const unsigned short* __restrict__ VMr,
    const float* __restrict__ PSr, int t0s, int Tcs, int isFirst, int nScan)
{
    __shared__ __align__(16) char smem[sizeof(ThSm2)];
    int tid = threadIdx.x;

    if ((int)blockIdx.x < nScan) {
        // ===================== SCAN (chunk c-1), 2 sites =====================
        float* part = (float*)smem;                 // [4][128] = 2 KB
        int sl = tid >> 7, hc = tid & 127;
        int lane = tid & 63, wid = tid >> 6;
        int site = blockIdx.x * 2 + sl;
        int cell = site * 128 + hc;

        float kp  = params[0 * NSH + cell];
        float ksP = params[1 * NSH + cell];
        float kgP = params[2 * NSH + cell];
        float gp  = params[3 * NSH + cell];
        float gL  = params[4 * NSH + cell];
        float qb  = params[5 * NSH + cell];
        float ga  = params[6 * NSH + cell];
        float kq  = ksP * (1.0f - gp);

        float wr[NRTAP];
#pragma unroll
        for (int i = 0; i < NRTAP; ++i) wr[i] = ga * rbuf[i * NSH + cell];

        float Sf, Ss, Sg, f[NRTAP];
        if (isFirst) {
            Sf = Ss = Sg = 0.0f;
#pragma unroll
            for (int i = 0; i < NRTAP; ++i) f[i] = 0.0f;
        } else {
            Sf = state[cell];
            Ss = state[NSH + cell];
            Sg = state[2 * NSH + cell];
#pragma unroll
            for (int i = 0; i < NRTAP; ++i) f[i] = fut[i * NSH + cell];
        }

        const unsigned* pep = PEr + cell;
        const unsigned short* vmp = VMr + cell;

#define LD_T(PE_, VM_, PS_, T_) { int t_ = (T_); bool ok_ = t_ < Tcs;          \
        PE_ = ok_ ? pep[(size_t)t_ * NSH] : 0u;                                \
        VM_ = ok_ ? vmp[(size_t)t_ * NSH] : (unsigned short)0;                 \
        PS_ = ok_ ? PSr[(size_t)t_ * 800 + site] : 0.0f; }

        unsigned peA[4], peB[4], peC[4], peD[4];
        unsigned short vmA[4], vmB[4], vmC[4], vmD[4];
        float psA[4], psB[4], psC[4], psD[4];
#pragma unroll
        for (int i = 0; i < 4; ++i) LD_T(peA[i], vmA[i], psA[i], i)
#pragma unroll
        for (int i = 0; i < 4; ++i) LD_T(peB[i], vmB[i], psB[i], 4 + i)
#pragma unroll
        for (int i = 0; i < 4; ++i) LD_T(peC[i], vmC[i], psC[i], 8 + i)
#pragma unroll
        for (int i = 0; i < 4; ++i) LD_T(peD[i], vmD[i], psD[i], 12 + i)

        int ngroups = (Tcs + 3) >> 2;
        for (int g = 0; g < ngroups; ++g) {
            int tb = g * 4;
            unsigned peE[4]; unsigned short vmE[4]; float psE[4];
#pragma unroll
            for (int i = 0; i < 4; ++i) LD_T(peE[i], vmE[i], psE[i], tb + 16 + i)

            float cs[4];
#pragma unroll
            for (int i = 0; i < 4; ++i) {
                cs[i] = 0.0f;
                if (tb + i < Tcs) {
                    float pl = h_val((unsigned short)(peA[i] & 0xffffu));
                    float ev = h_val((unsigned short)(peA[i] >> 16));
                    float vm = h_val(vmA[i]);
                    float ps = psA[i];

                    float x1 = Sf + ps;
                    float qf = fminf(x1, vm);
                    Sf = fmaxf(x1 - vm, 0.0f);
                    float H  = fmaxf(Ss + pl + qf - ev, 0.0f);
                    float qp = fmaxf(kp * (H - gL), 0.0f);
                    float mh = fminf(H, gL);
                    float qs = ksP * mh;
                    Ss = H - qp - qs;
                    float qg = fmaf(kgP, fmaf(qs, gp, Sg), qb);
                    Sg = Sg - qg;
                    float qt = qp + kq * mh + qg;
#pragma unroll
                    for (int j = 0; j < NRTAP; ++j) f[j] = fmaf(wr[j], qt, f[j]);
                    cs[i] = f[0];
#pragma unroll
                    for (int j = 0; j < NRTAP - 1; ++j) f[j] = f[j + 1];
                    f[NRTAP - 1] = 0.0f;
                }
            }
#pragma unroll
            for (int i = 0; i < 4; ++i) {
                float c = cs[i];
#pragma unroll
                for (int off = 32; off; off >>= 1) c += __shfl_xor(c, off);
                cs[i] = c;
            }
            if (lane == 0) {
#pragma unroll
                for (int i = 0; i < 4; ++i)
                    if (tb + i < Tcs) part[wid * 128 + tb + i] = cs[i];
            }
#pragma unroll
            for (int i = 0; i < 4; ++i) {
                peA[i] = peB[i]; peB[i] = peC[i]; peC[i] = peD[i]; peD[i] = peE[i];
                vmA[i] = vmB[i]; vmB[i] = vmC[i]; vmC[i] = vmD[i]; vmD[i] = vmE[i];
                psA[i] = psB[i]; psB[i] = psC[i]; psC[i] = psD[i]; psD[i] = psE[i];
            }
        }
#undef LD_T

        state[cell]           = Sf;
        state[NSH + cell]     = Ss;
        state[2 * NSH + cell] = Sg;
#pragma unroll
        for (int i = 0; i < NRTAP; ++i) fut[i * NSH + cell] = f[i];

        __syncthreads();
        {
            int sl2 = tid >> 7, tl = tid & 127;
            for (int t = tl; t < Tcs; t += 128)
                out[(size_t)(t0s + t) * 800 + blockIdx.x * 2 + sl2] =
                    part[(sl2 * 2) * 128 + t] + part[(sl2 * 2 + 1) * 128 + t];
        }
        return;
    }

    // ===================== TIMEHEAD tile (32 rows of chunk c) ===============
    ThSm2* sm = (ThSm2*)smem;
    int m0 = ((int)blockIdx.x - nScan) * 32;
    int wid = tid >> 6, lane = tid & 63;
    int l15 = lane & 15, l4 = lane >> 4;
    int n0w = wid * 32;                      // wave's 32 hidden cols

    if (tid < 32) {
        int row = m0 + tid;
        const float* xp = &x[((size_t)t0h * 800 + row) * 6];
        float P = xp[0], E = xp[1], T1 = xp[2], T2 = xp[3];
        sm->xt[tid][0] = P;  sm->xt[tid][1] = E;     sm->xt[tid][2] = T1;
        sm->xt[tid][3] = T2; sm->xt[tid][4] = xp[4]; sm->xt[tid][5] = xp[5];
        float den = T2 - T1;
        float cf = (T1 + T2) / ((den == 0.0f) ? 1.0f : den);
        cf = fminf(fmaxf(cf, -0.999999f), 0.999999f);
        float vf = acosf(cf) * (1.0f / 3.1415f);
        vf = (T1 >= 0.0f) ? 0.0f : vf;
        vf = (T2 <= 0.0f) ? 1.0f : vf;
        sm->pls[tid] = P * (1.0f - vf);
        sm->evs[tid] = E;
        sm->psv[tid] = P * vf;
        PSw[row] = P * vf;
    }
    __syncthreads();   // B1: xt ready

    // ---- L1: thread = (k-octet jg, row-quad rg) -> swizzled Ah ----
    {
        int jg = tid & 31, rg = tid >> 5;
        int j0 = jg * 8;
        float4 wA[6], wB[6];
#pragma unroll
        for (int c = 0; c < 6; ++c) {
            wA[c] = *(const float4*)&w1T[c * 256 + j0];
            wB[c] = *(const float4*)&w1T[c * 256 + j0 + 4];
        }
#pragma unroll
        for (int rr = 0; rr < 4; ++rr) {
            int r = rg * 4 + rr;
            int srow = (m0 + r) % 800;
            const float* bp = &basec[(size_t)srow * 256 + j0];
            float4 b0 = *(const float4*)bp;
            float4 b1 = *(const float4*)(bp + 4);
            float a[8] = {b0.x, b0.y, b0.z, b0.w, b1.x, b1.y, b1.z, b1.w};
#pragma unroll
            for (int c = 0; c < 6; ++c) {
                float xv = sm->xt[r][c];
                a[0] = fmaf(xv, wA[c].x, a[0]);
                a[1] = fmaf(xv, wA[c].y, a[1]);
                a[2] = fmaf(xv, wA[c].z, a[2]);
                a[3] = fmaf(xv, wA[c].w, a[3]);
                a[4] = fmaf(xv, wB[c].x, a[4]);
                a[5] = fmaf(xv, wB[c].y, a[5]);
                a[6] = fmaf(xv, wB[c].z, a[6]);
                a[7] = fmaf(xv, wB[c].w, a[7]);
            }
            f16x8 hv;
#pragma unroll
            for (int e = 0; e < 8; ++e) hv[e] = (_Float16)tanh_fast(a[e]);
            sm->Ah[ah_swz32(jg, r)] = hv;
        }
    }
    __syncthreads();   // B2: Ah ready

    // ---- GEMM: nf = ch*2 + cf, col = ch*128 + n0w + cf*16 + l15 ----
    f32x4 acc[2][6];
#pragma unroll
    for (int ch = 0; ch < 3; ++ch)
#pragma unroll
        for (int cf = 0; cf < 2; ++cf) {
            float bb = b2[ch * 128 + n0w + cf * 16 + l15];
            acc[0][ch * 2 + cf] = (f32x4){bb, bb, bb, bb};
            acc[1][ch * 2 + cf] = (f32x4){bb, bb, bb, bb};
        }
    f16x8 bf[6], bfn[6];
#pragma unroll
    for (int ch = 0; ch < 3; ++ch)
#pragma unroll
        for (int cf = 0; cf < 2; ++cf)
            bf[ch * 2 + cf] = w2B[(size_t)l4 * 384 + ch * 128 + n0w + cf * 16 + l15];
    for (int ks = 0; ks < 8; ++ks) {
        if (ks < 7) {
#pragma unroll
            for (int ch = 0; ch < 3; ++ch)
#pragma unroll
                for (int cf = 0; cf < 2; ++cf)
                    bfn[ch * 2 + cf] = w2B[(size_t)(ks + 1) * 1536 + l4 * 384
                                           + ch * 128 + n0w + cf * 16 + l15];
        }
        f16x8 af[2];
#pragma unroll
        for (int mf = 0; mf < 2; ++mf)
            af[mf] = sm->Ah[ah_swz32(ks * 4 + l4, mf * 16 + l15)];
#pragma unroll
        for (int mf = 0; mf < 2; ++mf)
#pragma unroll
            for (int nf = 0; nf < 6; ++nf)
                acc[mf][nf] = __builtin_amdgcn_mfma_f32_16x16x32_f16(
                    af[mf], bf[nf], acc[mf][nf], 0, 0, 0);
        if (ks < 7) {
#pragma unroll
            for (int nf = 0; nf < 6; ++nf) bf[nf] = bfn[nf];
        }
    }

    // ---- epilogue: same-lane pl/ev/vm -> packed direct stores ----
#pragma unroll
    for (int mf = 0; mf < 2; ++mf) {
#pragma unroll
        for (int cf = 0; cf < 2; ++cf) {
            int col = n0w + cf * 16 + l15;
#pragma unroll
            for (int rr = 0; rr < 4; ++rr) {
                int r = mf * 16 + l4 * 4 + rr;
                float vp = acc[mf][0 * 2 + cf][rr];
                float ve = acc[mf][1 * 2 + cf][rr];
                float vv = acc[mf][2 * 2 + cf][rr];
                float opl = sm->pls[r] * fminf(fmaxf(vp * (1.0f / 3.0f) + 0.5f, 0.0f), 1.0f);
                float oev = sm->evs[r] * fmaxf(ve, 0.0f) * 2.0f;
                float ovm = fminf(__expf(vv), 60000.0f);
                unsigned pe = (unsigned)h_bits((_Float16)opl)
                            | ((unsigned)h_bits((_Float16)oev) << 16);
                size_t gidx = (size_t)(m0 + r) * 128 + col;
                PEw[gidx] = pe;
                VMw[gidx] = h_bits((_Float16)ovm);
            }
        }
    }
}

// ---------------------------------------------------------------------------
extern "C" void kernel_launch(void* const* d_in, const int* in_sizes, int n_in,
                              void* d_out, int out_size, void* d_ws, size_t ws_size,
                              hipStream_t stream)
{
    const float* x      = (const float*)d_in[0];
    const float* xc     = (const float*)d_in[1];
    const float* fcW1_w = (const float*)d_in[2];
    const float* fcW1_b = (const float*)d_in[3];
    const float* fcW2_w = (const float*)d_in[4];
    const float* fcW2_b = (const float*)d_in[5];
    const float* fcT1_w = (const float*)d_in[6];
    const float* fcT1_b = (const float*)d_in[7];
    const float* fcT2_w = (const float*)d_in[8];
    const float* fcT2_b = (const float*)d_in[9];
    const float* fcR1_w = (const float*)d_in[10];
    const float* fcR1_b = (const float*)d_in[11];
    const float* fcR2_w = (const float*)d_in[12];
    const float* fcR2_b = (const float*)d_in[13];
    float* out = (float*)d_out;

    char* wsb = (char*)d_ws;
    size_t off = 0;
    float* params = (float*)(wsb + off); off += (size_t)7 * NSH * 4;
    float* rbuf   = (float*)(wsb + off); off += (size_t)NRTAP * NSH * 4;
    float* basec  = (float*)(wsb + off); off += 800 * 256 * 4;
    float* h1w    = (float*)(wsb + off); off += 800 * 256 * 4;
    float* h1r    = (float*)(wsb + off); off += 800 * 256 * 4;
    float* state  = (float*)(wsb + off); off += (size_t)3 * NSH * 4;
    float* fut    = (float*)(wsb + off); off += (size_t)NRTAP * NSH * 4;
    _Float16* w2s = (_Float16*)(wsb + off); off += 98304 * 2;
    size_t fixedB = off;

    // per-timestep bytes in one chunk buffer: PE(4) + VM(2) per cell + PS row
    const size_t perT = (size_t)NSH * 6 + 800 * 4;
    long avail = (long)ws_size - (long)fixedB - 4096;
    int Tc = (int)(avail / (long)(2 * perT));
    if (Tc > 128) Tc = 128;     // smaller chunks: more scan/th overlap, part[] fits
    Tc &= ~3;
    if (Tc < 4) Tc = 4;

    unsigned*       PE0 = (unsigned*)(wsb + off);       off += (size_t)Tc * NSH * 4;
    unsigned short* VM0 = (unsigned short*)(wsb + off); off += (size_t)Tc * NSH * 2;
    float*          PS0 = (float*)(wsb + off);          off += (size_t)Tc * 800 * 4;
    unsigned*       PE1 = (unsigned*)(wsb + off);       off += (size_t)Tc * NSH * 4;
    unsigned short* VM1 = (unsigned short*)(wsb + off); off += (size_t)Tc * NSH * 2;
    float*          PS1 = (float*)(wsb + off);          off += (size_t)Tc * 800 * 4;

    k_prep_w2h<<<384, 256, 0, stream>>>(fcT2_w, w2s);
    k_site_l1<<<800, 256, 0, stream>>>(xc, fcW1_w, fcW1_b, fcR1_w, fcR1_b,
                                       fcT1_w, fcT1_b, h1w, h1r, basec);
    k_whead<<<dim3(100, 7), 128, 0, stream>>>(h1w, fcW2_w, fcW2_b, params);
    k_softmax_ga<<<800, 128, 0, stream>>>(params + (size_t)6 * NSH);
    k_rhead<<<dim3(100, 15), 128, 0, stream>>>(h1r, fcR2_w, fcR2_b, rbuf);

    int nch = (NTIME + Tc - 1) / Tc;
    for (int c = 0; c <= nch; ++c) {
        int nScan = (c > 0) ? 400 : 0;
        int Tch = 0;
        if (c < nch) { Tch = NTIME - c * Tc; if (Tch > Tc) Tch = Tc; }
        int rowsH = Tch * 800;
        int thB = rowsH / 32;
        int grid = nScan + thB;
        if (grid == 0) continue;
        int t0s = (c - 1) * Tc;
        int Tcs = 0;
        if (c > 0) { Tcs = NTIME - t0s; if (Tcs > Tc) Tcs = Tc; }
        unsigned*       PEw = (c & 1) ? PE1 : PE0;
        unsigned short* VMw = (c & 1) ? VM1 : VM0;
        float*          PSw = (c & 1) ? PS1 : PS0;
        const unsigned*       PEr = ((c - 1) & 1) ? PE1 : PE0;
        const unsigned short* VMr = ((c - 1) & 1) ? VM1 : VM0;
        const float*          PSr = ((c - 1) & 1) ? PS1 : PS0;
        k_combo4<<<grid, 256, 0, stream>>>(
            x, fcT1_w, basec, (const f16x8*)w2s, fcT2_b, params, rbuf,
            state, fut, out,
            PEw, VMw, PSw, c * Tc, rowsH,
            PEr, VMr, PSr, t0s, Tcs, (c == 1) ? 1 : 0, nScan);
    }
}